// Round 1
// baseline (647.114 us; speedup 1.0000x reference)
//
#include <hip/hip_runtime.h>
#include <hip/hip_bf16.h>

// out = relu((x * drop_mask) @ weight @ support)
// Fused via associativity: W = weight @ support (128x128, precomputed per launch),
// then out = relu(xd @ W) -- a single memory-bound N=500k GEMM with K=N_out=128.

#define D 128
#define LDS_PITCH 136  // +8 bf16 (16 B) pad: breaks the 256B-stride bank pattern

typedef __attribute__((ext_vector_type(8))) short short8;
typedef __attribute__((ext_vector_type(4))) float f32x4;

__device__ __forceinline__ short f2bf(float f) {
    union { __hip_bfloat16 h; short s; } u;
    u.h = __float2bfloat16(f);
    return u.s;
}

// --- Kernel 1: Wt[n][k] = (weight @ support)[k][n], bf16, into d_ws ---
// grid 128 (i = output row of W), block 128 (j = output col of W)
__global__ void wprod_kernel(const float* __restrict__ weight,
                             const float* __restrict__ support,
                             unsigned short* __restrict__ wt) {
    __shared__ float wrow[D];
    const int i = blockIdx.x;
    const int j = threadIdx.x;
    wrow[j] = weight[i * D + j];
    __syncthreads();
    float acc = 0.f;
#pragma unroll 8
    for (int k = 0; k < D; ++k)
        acc = fmaf(wrow[k], support[k * D + j], acc);
    union { __hip_bfloat16 h; unsigned short s; } u;
    u.h = __float2bfloat16(acc);
    // store transposed: row n=j holds W[.][j] over k -> contiguous B-fragments
    wt[(size_t)j * D + i] = u.s;
}

// --- Kernel 2: out = relu(xd @ W), one 16-row slab per wave per iteration ---
__global__ __launch_bounds__(256, 4) void gcn_fused(
    const float* __restrict__ x, const float* __restrict__ mask,
    const unsigned short* __restrict__ wt, float* __restrict__ out,
    int nslabs) {
    __shared__ __align__(16) unsigned short lw[D * LDS_PITCH];

    // cooperative load of Wt (128x128 bf16 = 2048 uint4) into padded LDS
    const uint4* src = reinterpret_cast<const uint4*>(wt);
    for (int c = threadIdx.x; c < 2048; c += 256) {
        const int n = c >> 4;          // Wt row (16 uint4 per 128-elem row)
        const int kc = (c & 15) << 3;  // k offset in elements
        *reinterpret_cast<uint4*>(&lw[n * LDS_PITCH + kc]) = src[c];
    }
    __syncthreads();

    const int lane = threadIdx.x & 63;
    const int m = lane & 15;    // A row within tile / C col within tile
    const int quad = lane >> 4; // k-subchunk selector / C row-quad

    const int wave = (blockIdx.x * blockDim.x + threadIdx.x) >> 6;
    const int nwaves = (gridDim.x * blockDim.x) >> 6;

    for (int s = wave; s < nslabs; s += nwaves) {
        const float* xr = x + ((size_t)s * 16 + m) * D + quad * 8;
        const float* mr = mask + ((size_t)s * 16 + m) * D + quad * 8;

        // Build A fragments for the full K=128: a[kk] covers k in [kk*32, kk*32+32)
        short8 a[4];
#pragma unroll
        for (int kk = 0; kk < 4; ++kk) {
            f32x4 x0 = *reinterpret_cast<const f32x4*>(xr + kk * 32);
            f32x4 x1 = *reinterpret_cast<const f32x4*>(xr + kk * 32 + 4);
            f32x4 m0 = *reinterpret_cast<const f32x4*>(mr + kk * 32);
            f32x4 m1 = *reinterpret_cast<const f32x4*>(mr + kk * 32 + 4);
            f32x4 p0 = x0 * m0;
            f32x4 p1 = x1 * m1;
            short8 v;
            v[0] = f2bf(p0[0]); v[1] = f2bf(p0[1]);
            v[2] = f2bf(p0[2]); v[3] = f2bf(p0[3]);
            v[4] = f2bf(p1[0]); v[5] = f2bf(p1[1]);
            v[6] = f2bf(p1[2]); v[7] = f2bf(p1[3]);
            a[kk] = v;
        }

        float* orow = out + (size_t)s * 16 * D;
#pragma unroll
        for (int n = 0; n < 8; ++n) {
            f32x4 acc = {0.f, 0.f, 0.f, 0.f};
#pragma unroll
            for (int kk = 0; kk < 4; ++kk) {
                const short8 b = *reinterpret_cast<const short8*>(
                    &lw[(n * 16 + m) * LDS_PITCH + kk * 32 + quad * 8]);
                acc = __builtin_amdgcn_mfma_f32_16x16x32_bf16(a[kk], b, acc, 0, 0, 0);
            }
            // C/D layout: col = n*16 + (lane&15), row = quad*4 + r
#pragma unroll
            for (int r = 0; r < 4; ++r) {
                const float v = acc[r];
                orow[(quad * 4 + r) * D + n * 16 + m] = v > 0.f ? v : 0.f;
            }
        }
    }
}

extern "C" void kernel_launch(void* const* d_in, const int* in_sizes, int n_in,
                              void* d_out, int out_size, void* d_ws, size_t ws_size,
                              hipStream_t stream) {
    const float* x = (const float*)d_in[0];
    const float* weight = (const float*)d_in[1];
    const float* support = (const float*)d_in[2];
    const float* mask = (const float*)d_in[3];
    float* out = (float*)d_out;
    unsigned short* wt = (unsigned short*)d_ws;  // 128*128 bf16 = 32 KB

    const int nrows = in_sizes[0] / D;   // 500000
    const int nslabs = nrows / 16;       // 31250 (exact)

    wprod_kernel<<<dim3(D), dim3(D), 0, stream>>>(weight, support, wt);
    gcn_fused<<<dim3(2048), dim3(256), 0, stream>>>(x, mask, wt, out, nslabs);
}